// Round 1
// baseline (1740.718 us; speedup 1.0000x reference)
//
#include <hip/hip_runtime.h>

#define NN 50000
#define NE 800000
#define FF 128
#define KF 8
#define DD 16
#define GG 512
#define BN_EPS 1e-5f

// ---------------- CSR build ----------------
__global__ void k_deg(const int* __restrict__ dst, int* __restrict__ deg) {
    int e = blockIdx.x * 256 + threadIdx.x;
    if (e < NE) atomicAdd(&deg[dst[e]], 1);
}

__global__ __launch_bounds__(1024) void k_scan(const int* __restrict__ deg, int* __restrict__ offs) {
    __shared__ int part[1024];
    int tid = threadIdx.x;
    const int chunk = (NN + 1023) / 1024;  // 49
    int base = tid * chunk;
    int s = 0;
    for (int i = 0; i < chunk; i++) {
        int idx = base + i;
        if (idx < NN) s += deg[idx];
    }
    part[tid] = s;
    __syncthreads();
    // Hillis-Steele inclusive scan
    for (int off = 1; off < 1024; off <<= 1) {
        int v = (tid >= off) ? part[tid - off] : 0;
        __syncthreads();
        part[tid] += v;
        __syncthreads();
    }
    int run = (tid == 0) ? 0 : part[tid - 1];
    for (int i = 0; i < chunk; i++) {
        int idx = base + i;
        if (idx < NN) { offs[idx] = run; run += deg[idx]; }
    }
    if (tid == 1023) offs[NN] = part[1023];
}

__global__ void k_fill(const int* __restrict__ src, const int* __restrict__ dst,
                       const int* __restrict__ offs, int* __restrict__ cnt,
                       int* __restrict__ csr) {
    int e = blockIdx.x * 256 + threadIdx.x;
    if (e < NE) {
        int d = dst[e];
        int p = atomicAdd(&cnt[d], 1);
        csr[offs[d] + p] = src[e];
    }
}

// ---------------- aggregation: Z[n] = Hin[n] + sum_{e: dst=n} Hin[src_e] ----------------
__global__ __launch_bounds__(256) void k_agg(const float* __restrict__ Hin,
                                             const int* __restrict__ offs,
                                             const int* __restrict__ csr,
                                             float* __restrict__ Z) {
    int n = blockIdx.x * 2 + (threadIdx.x >> 7);
    int f = threadIdx.x & 127;
    float acc = Hin[(size_t)n * FF + f];
    int e0 = offs[n], e1 = offs[n + 1];
    for (int e = e0; e < e1; e++) {
        int s = csr[e];
        acc += Hin[(size_t)s * FF + f];
    }
    Z[(size_t)n * FF + f] = acc;
}

// ---------------- full GEMM: C[N,128] = act(A[N,128] @ W[128,128] + b) ----------------
template <bool RELU>
__global__ __launch_bounds__(256) void gemm128(const float* __restrict__ A,
                                               const float* __restrict__ W,
                                               const float* __restrict__ bias,
                                               float* __restrict__ C, int nrows) {
    __shared__ float As[128][33];  // [r][f-chunk], +1 pad: conflict-free
    __shared__ float Ws[32][128];  // [f-chunk][c]
    int row0 = blockIdx.x * 128;
    int tid = threadIdx.x;
    int tr = (tid >> 4) << 3;  // 0..120
    int tc = (tid & 15) << 3;  // 0..120
    float acc[8][8];
#pragma unroll
    for (int i = 0; i < 8; i++)
#pragma unroll
        for (int j = 0; j < 8; j++) acc[i][j] = 0.f;

    for (int f0 = 0; f0 < 128; f0 += 32) {
#pragma unroll
        for (int i = 0; i < 16; i++) {
            int l = tid + i * 256;
            int r = l >> 5, f = l & 31;
            int gr = row0 + r;
            if (gr >= nrows) gr = nrows - 1;  // clamp (discarded at store)
            As[r][f] = A[(size_t)gr * 128 + f0 + f];
        }
#pragma unroll
        for (int i = 0; i < 16; i++) {
            int l = tid + i * 256;
            int f = l >> 7, c = l & 127;
            Ws[f][c] = W[(size_t)(f0 + f) * 128 + c];
        }
        __syncthreads();
#pragma unroll 8
        for (int f = 0; f < 32; f++) {
            float a[8], w[8];
#pragma unroll
            for (int i = 0; i < 8; i++) a[i] = As[tr + i][f];
#pragma unroll
            for (int j = 0; j < 8; j++) w[j] = Ws[f][tc + j];
#pragma unroll
            for (int i = 0; i < 8; i++)
#pragma unroll
                for (int j = 0; j < 8; j++) acc[i][j] = fmaf(a[i], w[j], acc[i][j]);
        }
        __syncthreads();
    }
#pragma unroll
    for (int i = 0; i < 8; i++) {
        int r = row0 + tr + i;
        if (r < nrows) {
#pragma unroll
            for (int j = 0; j < 8; j++) {
                float v = acc[i][j] + bias[tc + j];
                if (RELU) v = fmaxf(v, 0.f);
                C[(size_t)r * 128 + tc + j] = v;
            }
        }
    }
}

// ---------------- block-diagonal GEMM (K blocks of 16x16) ----------------
template <bool RELU>
__global__ __launch_bounds__(256) void k_bdgemm(const float* __restrict__ A,
                                                const float* __restrict__ W,  // [K,16,16]
                                                const float* __restrict__ bias,  // [K*16]
                                                float* __restrict__ C, int nrows) {
    __shared__ float As[2][FF];
    int half = threadIdx.x >> 7;
    int r = blockIdx.x * 2 + half;
    int c = threadIdx.x & 127;
    As[half][c] = A[(size_t)r * FF + c];
    __syncthreads();
    int k = c >> 4, j = c & 15;
    const float* w = W + k * 256 + j;
    const float* a = &As[half][k << 4];
    float acc = bias[c];
#pragma unroll
    for (int i = 0; i < 16; i++) acc = fmaf(a[i], w[i * 16], acc);
    if (RELU) acc = fmaxf(acc, 0.f);
    C[(size_t)r * FF + c] = acc;
}

// ---------------- BN stats: sum & sumsq per column ----------------
__global__ __launch_bounds__(256) void k_stats(const float* __restrict__ X,
                                               float* __restrict__ st, int nrows) {
    int c = threadIdx.x & 127;
    int half = threadIdx.x >> 7;
    int rpb = (nrows + gridDim.x - 1) / gridDim.x;
    int r0 = blockIdx.x * rpb;
    int r1 = min(r0 + rpb, nrows);
    float s = 0.f, sq = 0.f;
    for (int r = r0 + half; r < r1; r += 2) {
        float v = X[(size_t)r * FF + c];
        s += v;
        sq += v * v;
    }
    atomicAdd(&st[c], s);
    atomicAdd(&st[FF + c], sq);
}

// ---------------- BN apply (+optional relu) ----------------
template <bool RELU>
__global__ __launch_bounds__(256) void k_bn(const float* __restrict__ X,
                                            const float* __restrict__ st,
                                            const float* __restrict__ g,
                                            const float* __restrict__ be,
                                            float* __restrict__ Y, int nrows) {
    int idx = blockIdx.x * 256 + threadIdx.x;  // float4 index
    int total = nrows * (FF / 4);
    if (idx >= total) return;
    int c4 = (idx & 31) * 4;
    float4 x = ((const float4*)X)[idx];
    float xs[4] = {x.x, x.y, x.z, x.w};
    float out[4];
    const float inv_n = 1.0f / (float)nrows;
#pragma unroll
    for (int t = 0; t < 4; t++) {
        int c = c4 + t;
        float mu = st[c] * inv_n;
        float var = st[FF + c] * inv_n - mu * mu;
        float v = (xs[t] - mu) * rsqrtf(var + BN_EPS) * g[c] + be[c];
        if (RELU) v = fmaxf(v, 0.f);
        out[t] = v;
    }
    ((float4*)Y)[idx] = make_float4(out[0], out[1], out[2], out[3]);
}

// ---------------- repack h0_W1 [K,F,d] -> Wcat [F, K*d] ----------------
__global__ void k_repack(const float* __restrict__ W1, float* __restrict__ Wcat) {
    int idx = blockIdx.x * 256 + threadIdx.x;
    if (idx < FF * FF) {
        int f = idx >> 7, c = idx & 127;
        int k = c >> 4, j = c & 15;
        Wcat[idx] = W1[k * (FF * DD) + f * DD + j];
    }
}

// ---------------- pooling: out[batch[n]*128 + c] += X[n*128 + c] (batch sorted) ----------------
__global__ __launch_bounds__(128) void k_pool(const float* __restrict__ X,
                                              const int* __restrict__ batch,
                                              float* __restrict__ out) {
    int c = threadIdx.x;
    int chunk = (NN + gridDim.x - 1) / gridDim.x;
    int r0 = blockIdx.x * chunk;
    int r1 = min(r0 + chunk, NN);
    if (r0 >= r1) return;
    float acc = 0.f;
    int cur = batch[r0];
    for (int r = r0; r < r1; r++) {
        int b = batch[r];
        if (b != cur) {
            atomicAdd(&out[(size_t)cur * FF + c], acc);
            acc = 0.f;
            cur = b;
        }
        acc += X[(size_t)r * FF + c];
    }
    atomicAdd(&out[(size_t)cur * FF + c], acc);
}

extern "C" void kernel_launch(void* const* d_in, const int* in_sizes, int n_in,
                              void* d_out, int out_size, void* d_ws, size_t ws_size,
                              hipStream_t stream) {
    const float* x = (const float*)d_in[0];
    const int* ei = (const int*)d_in[1];
    const int* src = ei;
    const int* dst = ei + NE;
    const int* batch = (const int*)d_in[2];
    const float* gc_W1 = (const float*)d_in[4];
    const float* gc_b1 = (const float*)d_in[5];
    const float* gc_W2 = (const float*)d_in[6];
    const float* gc_b2 = (const float*)d_in[7];
    const float* gc_g = (const float*)d_in[8];
    const float* gc_be = (const float*)d_in[9];
    const float* h0_W1 = (const float*)d_in[10];
    const float* h0_b1 = (const float*)d_in[11];
    const float* h0_W2 = (const float*)d_in[12];
    const float* h0_b2 = (const float*)d_in[13];
    const float* h0_g = (const float*)d_in[14];
    const float* h0_be = (const float*)d_in[15];
    const float* h1_W1 = (const float*)d_in[16];
    const float* h1_b1 = (const float*)d_in[17];
    const float* h1_W2 = (const float*)d_in[18];
    const float* h1_b2 = (const float*)d_in[19];
    const float* h1_g = (const float*)d_in[20];
    const float* h1_be = (const float*)d_in[21];

    const size_t NF = (size_t)NN * FF;
    float* H = (float*)d_ws;
    float* A = H + NF;
    float* B = A + NF;
    float* Wcat = B + NF;
    float* stats = Wcat + FF * FF;  // 5 * 256 floats
    int* deg = (int*)(stats + 5 * 256);
    int* cnt = deg + NN;
    int* offs = cnt + NN;
    int* csr = offs + (NN + 4);

    // zero: deg+cnt (contiguous), stats, d_out
    hipMemsetAsync(deg, 0, (size_t)2 * NN * sizeof(int), stream);
    hipMemsetAsync(stats, 0, 5 * 256 * sizeof(float), stream);
    hipMemsetAsync(d_out, 0, (size_t)GG * KF * DD * sizeof(float), stream);

    // CSR build
    k_deg<<<(NE + 255) / 256, 256, 0, stream>>>(dst, deg);
    k_scan<<<1, 1024, 0, stream>>>(deg, offs);
    k_fill<<<(NE + 255) / 256, 256, 0, stream>>>(src, dst, offs, cnt, csr);

    const int gemm_grid = (NN + 127) / 128;  // 391
    const int bn_grid = (NN * (FF / 4) + 255) / 256;  // 6250

    // GC layers
    const float* hin = x;
    for (int i = 0; i < 3; i++) {
        k_agg<<<NN / 2, 256, 0, stream>>>(hin, offs, csr, A);
        gemm128<true><<<gemm_grid, 256, 0, stream>>>(A, gc_W1 + (size_t)i * FF * FF,
                                                     gc_b1 + i * FF, B, NN);
        gemm128<false><<<gemm_grid, 256, 0, stream>>>(B, gc_W2 + (size_t)i * FF * FF,
                                                      gc_b2 + i * FF, A, NN);
        k_stats<<<128, 256, 0, stream>>>(A, stats + i * 256, NN);
        if (i < 2)
            k_bn<true><<<bn_grid, 256, 0, stream>>>(A, stats + i * 256, gc_g + i * FF,
                                                    gc_be + i * FF, H, NN);
        else
            k_bn<false><<<bn_grid, 256, 0, stream>>>(A, stats + i * 256, gc_g + i * FF,
                                                     gc_be + i * FF, H, NN);
        hin = H;
    }

    // head layer 0: agg on h shared across K; stacked first linear; block-diag second
    k_repack<<<(FF * FF + 255) / 256, 256, 0, stream>>>(h0_W1, Wcat);
    k_agg<<<NN / 2, 256, 0, stream>>>(H, offs, csr, A);
    gemm128<true><<<gemm_grid, 256, 0, stream>>>(A, Wcat, h0_b1, B, NN);
    k_bdgemm<false><<<NN / 2, 256, 0, stream>>>(B, h0_W2, h0_b2, A, NN);
    k_stats<<<128, 256, 0, stream>>>(A, stats + 3 * 256, NN);
    k_bn<true><<<bn_grid, 256, 0, stream>>>(A, stats + 3 * 256, h0_g, h0_be, H, NN);

    // head layer 1: aggregate stacked [N, K*d]; two block-diag linears; BN (no relu)
    k_agg<<<NN / 2, 256, 0, stream>>>(H, offs, csr, A);
    k_bdgemm<true><<<NN / 2, 256, 0, stream>>>(A, h1_W1, h1_b1, B, NN);
    k_bdgemm<false><<<NN / 2, 256, 0, stream>>>(B, h1_W2, h1_b2, A, NN);
    k_stats<<<128, 256, 0, stream>>>(A, stats + 4 * 256, NN);
    k_bn<false><<<bn_grid, 256, 0, stream>>>(A, stats + 4 * 256, h1_g, h1_be, B, NN);

    // pool into d_out [G, K, d] == [G, 128]
    k_pool<<<512, 128, 0, stream>>>(B, batch, (float*)d_out);
}

// Round 2
// 976.497 us; speedup vs baseline: 1.7826x; 1.7826x over previous
//
#include <hip/hip_runtime.h>

#define NN 50000
#define NE 800000
#define FF 128
#define KF 8
#define DD 16
#define GG 512
#define BN_EPS 1e-5f

// ---------------- CSR build ----------------
__global__ void k_deg(const int* __restrict__ dst, int* __restrict__ deg) {
    int e = blockIdx.x * 256 + threadIdx.x;
    if (e < NE) atomicAdd(&deg[dst[e]], 1);
}

__global__ __launch_bounds__(1024) void k_scan(const int* __restrict__ deg, int* __restrict__ offs) {
    __shared__ int part[1024];
    int tid = threadIdx.x;
    const int chunk = (NN + 1023) / 1024;  // 49
    int base = tid * chunk;
    int s = 0;
    for (int i = 0; i < chunk; i++) {
        int idx = base + i;
        if (idx < NN) s += deg[idx];
    }
    part[tid] = s;
    __syncthreads();
    for (int off = 1; off < 1024; off <<= 1) {
        int v = (tid >= off) ? part[tid - off] : 0;
        __syncthreads();
        part[tid] += v;
        __syncthreads();
    }
    int run = (tid == 0) ? 0 : part[tid - 1];
    for (int i = 0; i < chunk; i++) {
        int idx = base + i;
        if (idx < NN) { offs[idx] = run; run += deg[idx]; }
    }
    if (tid == 1023) offs[NN] = part[1023];
}

__global__ void k_fill(const int* __restrict__ src, const int* __restrict__ dst,
                       const int* __restrict__ offs, int* __restrict__ cnt,
                       int* __restrict__ csr) {
    int e = blockIdx.x * 256 + threadIdx.x;
    if (e < NE) {
        int d = dst[e];
        int p = atomicAdd(&cnt[d], 1);
        csr[offs[d] + p] = src[e];
    }
}

// ---------------- aggregation with fused (optional) BN affine (+relu) on load ------
// Z[n] = f(X[n]) + sum_{e: dst=n} f(X[src_e]),  f(v) = relu?(a_c*v + b_c)
template <bool BN, bool RELU>
__global__ __launch_bounds__(256) void k_agg(const float4* __restrict__ X,
                                             const int* __restrict__ offs,
                                             const int* __restrict__ csr,
                                             const float* __restrict__ st,
                                             const float* __restrict__ g,
                                             const float* __restrict__ be,
                                             float4* __restrict__ Z) {
    int grp = threadIdx.x >> 5;   // node within block (0..7)
    int lane = threadIdx.x & 31;  // float4 column
    int n = blockIdx.x * 8 + grp;

    float4 a4 = make_float4(1.f, 1.f, 1.f, 1.f);
    float4 b4 = make_float4(0.f, 0.f, 0.f, 0.f);
    if (BN) {
        const float inv_n = 1.0f / (float)NN;
        float av[4], bv[4];
#pragma unroll
        for (int t = 0; t < 4; t++) {
            int c = lane * 4 + t;
            float mu = st[c] * inv_n;
            float var = st[FF + c] * inv_n - mu * mu;
            float a = g[c] * rsqrtf(var + BN_EPS);
            av[t] = a;
            bv[t] = be[c] - mu * a;
        }
        a4 = make_float4(av[0], av[1], av[2], av[3]);
        b4 = make_float4(bv[0], bv[1], bv[2], bv[3]);
    }

    auto apply = [&](float4 v) -> float4 {
        if (BN) {
            v.x = fmaf(v.x, a4.x, b4.x);
            v.y = fmaf(v.y, a4.y, b4.y);
            v.z = fmaf(v.z, a4.z, b4.z);
            v.w = fmaf(v.w, a4.w, b4.w);
        }
        if (RELU) {
            v.x = fmaxf(v.x, 0.f);
            v.y = fmaxf(v.y, 0.f);
            v.z = fmaxf(v.z, 0.f);
            v.w = fmaxf(v.w, 0.f);
        }
        return v;
    };

    float4 acc = apply(X[(size_t)n * 32 + lane]);
    int e0 = offs[n], e1 = offs[n + 1];
    int e = e0;
    for (; e + 4 <= e1; e += 4) {
        int s0 = csr[e], s1 = csr[e + 1], s2 = csr[e + 2], s3 = csr[e + 3];
        float4 v0 = X[(size_t)s0 * 32 + lane];
        float4 v1 = X[(size_t)s1 * 32 + lane];
        float4 v2 = X[(size_t)s2 * 32 + lane];
        float4 v3 = X[(size_t)s3 * 32 + lane];
        v0 = apply(v0); v1 = apply(v1); v2 = apply(v2); v3 = apply(v3);
        acc.x += v0.x + v1.x + v2.x + v3.x;
        acc.y += v0.y + v1.y + v2.y + v3.y;
        acc.z += v0.z + v1.z + v2.z + v3.z;
        acc.w += v0.w + v1.w + v2.w + v3.w;
    }
    for (; e < e1; e++) {
        int s = csr[e];
        float4 v = apply(X[(size_t)s * 32 + lane]);
        acc.x += v.x; acc.y += v.y; acc.z += v.z; acc.w += v.w;
    }
    Z[(size_t)n * 32 + lane] = acc;
}

// ---------------- full GEMM: C[N,128] = act(A[N,128] @ W[128,128] + b), optional stats
template <bool RELU, bool STATS>
__global__ __launch_bounds__(256) void gemm128(const float* __restrict__ A,
                                               const float* __restrict__ W,
                                               const float* __restrict__ bias,
                                               float* __restrict__ C, int nrows,
                                               float* __restrict__ st) {
    __shared__ float As[128][33];  // +1 pad: a-broadcast reads conflict-free
    __shared__ float Ws[32][128];
    int row0 = blockIdx.x * 128;
    int tid = threadIdx.x;
    int tr = (tid >> 4) << 3;  // 0..120
    int tc = (tid & 15) << 3;  // 0..120
    float acc[8][8];
#pragma unroll
    for (int i = 0; i < 8; i++)
#pragma unroll
        for (int j = 0; j < 8; j++) acc[i][j] = 0.f;

    for (int f0 = 0; f0 < 128; f0 += 32) {
        // stage A chunk [128 rows][32 feats]: 1024 float4s, 4 per thread
#pragma unroll
        for (int i = 0; i < 4; i++) {
            int l = tid + i * 256;          // 0..1023
            int r = l >> 3, q = l & 7;      // row, float4-col
            int gr = row0 + r;
            if (gr >= nrows) gr = nrows - 1;  // clamp (excluded from store/stats)
            float4 v = ((const float4*)A)[(size_t)gr * 32 + (f0 >> 2) + q];
            As[r][q * 4 + 0] = v.x;
            As[r][q * 4 + 1] = v.y;
            As[r][q * 4 + 2] = v.z;
            As[r][q * 4 + 3] = v.w;
        }
        // stage W chunk [32 feats][128 cols]: 1024 float4s
#pragma unroll
        for (int i = 0; i < 4; i++) {
            int l = tid + i * 256;
            int f = l >> 5, q = l & 31;
            ((float4*)&Ws[f][0])[q] = ((const float4*)W)[(size_t)(f0 + f) * 32 + q];
        }
        __syncthreads();
#pragma unroll 8
        for (int f = 0; f < 32; f++) {
            float a[8];
#pragma unroll
            for (int i = 0; i < 8; i++) a[i] = As[tr + i][f];
            float4 w04 = *(const float4*)&Ws[f][tc];
            float4 w48 = *(const float4*)&Ws[f][tc + 4];
            float w[8] = {w04.x, w04.y, w04.z, w04.w, w48.x, w48.y, w48.z, w48.w};
#pragma unroll
            for (int i = 0; i < 8; i++)
#pragma unroll
                for (int j = 0; j < 8; j++) acc[i][j] = fmaf(a[i], w[j], acc[i][j]);
        }
        __syncthreads();
    }

    float cs[8], cq[8];
#pragma unroll
    for (int j = 0; j < 8; j++) { cs[j] = 0.f; cq[j] = 0.f; }
#pragma unroll
    for (int i = 0; i < 8; i++) {
        int r = row0 + tr + i;
        if (r < nrows) {
#pragma unroll
            for (int j = 0; j < 8; j++) {
                float v = acc[i][j] + bias[tc + j];
                if (RELU) v = fmaxf(v, 0.f);
                C[(size_t)r * 128 + tc + j] = v;
                if (STATS) { cs[j] += v; cq[j] += v * v; }
            }
        }
    }
    if (STATS) {
        // LDS column reduce (reuse As/Ws), then 2 atomics per column per block
        float* S1 = &As[0][0];
        float* S2 = &Ws[0][0];
        int grp = tid >> 4;  // 0..15
        __syncthreads();
#pragma unroll
        for (int j = 0; j < 8; j++) {
            S1[grp * 128 + tc + j] = cs[j];
            S2[grp * 128 + tc + j] = cq[j];
        }
        __syncthreads();
        if (tid < 128) {
            float s = 0.f, q = 0.f;
#pragma unroll
            for (int gi = 0; gi < 16; gi++) {
                s += S1[gi * 128 + tid];
                q += S2[gi * 128 + tid];
            }
            atomicAdd(&st[tid], s);
            atomicAdd(&st[FF + tid], q);
        }
    }
}

// ---------------- block-diagonal GEMM (K blocks of 16x16), 8 nodes/block ----------
template <bool RELU>
__global__ __launch_bounds__(256) void k_bdgemm(const float4* __restrict__ A,
                                                const float* __restrict__ W,  // [K,16,16]
                                                const float4* __restrict__ bias,
                                                float4* __restrict__ C) {
    __shared__ float As[8][128];
    __shared__ float Ws[KF * 256];  // 2048 floats
    int grp = threadIdx.x >> 5, lane = threadIdx.x & 31;
    int n = blockIdx.x * 8 + grp;
    ((float4*)&As[grp][0])[lane] = A[(size_t)n * 32 + lane];
    ((float4*)Ws)[threadIdx.x] = ((const float4*)W)[threadIdx.x];
    ((float4*)Ws)[256 + threadIdx.x] = ((const float4*)W)[256 + threadIdx.x];
    __syncthreads();
    int k = lane >> 2, jb = (lane & 3) * 4;  // cols k*16+jb.. = lane*4..
    const float* a = &As[grp][k * 16];
    float4 acc = bias[lane];
#pragma unroll
    for (int i = 0; i < 16; i++) {
        float av = a[i];
        float4 wv = *(const float4*)&Ws[k * 256 + i * 16 + jb];
        acc.x = fmaf(av, wv.x, acc.x);
        acc.y = fmaf(av, wv.y, acc.y);
        acc.z = fmaf(av, wv.z, acc.z);
        acc.w = fmaf(av, wv.w, acc.w);
    }
    if (RELU) {
        acc.x = fmaxf(acc.x, 0.f);
        acc.y = fmaxf(acc.y, 0.f);
        acc.z = fmaxf(acc.z, 0.f);
        acc.w = fmaxf(acc.w, 0.f);
    }
    C[(size_t)n * 32 + lane] = acc;
}

// ---------------- BN stats (standalone, for bdgemm outputs) ----------------
__global__ __launch_bounds__(256) void k_stats(const float* __restrict__ X,
                                               float* __restrict__ st, int nrows) {
    int c = threadIdx.x & 127;
    int half = threadIdx.x >> 7;
    int rpb = (nrows + gridDim.x - 1) / gridDim.x;
    int r0 = blockIdx.x * rpb;
    int r1 = min(r0 + rpb, nrows);
    float s = 0.f, sq = 0.f;
    for (int r = r0 + half; r < r1; r += 2) {
        float v = X[(size_t)r * FF + c];
        s += v;
        sq += v * v;
    }
    atomicAdd(&st[c], s);
    atomicAdd(&st[FF + c], sq);
}

// ---------------- repack h0_W1 [K,F,d] -> Wcat [F, K*d] ----------------
__global__ void k_repack(const float* __restrict__ W1, float* __restrict__ Wcat) {
    int idx = blockIdx.x * 256 + threadIdx.x;
    if (idx < FF * FF) {
        int f = idx >> 7, c = idx & 127;
        int k = c >> 4, j = c & 15;
        Wcat[idx] = W1[k * (FF * DD) + f * DD + j];
    }
}

// ---------------- pooling with fused final BN: out[g,c] = a_c*sum + cnt_g*b_c ------
__global__ __launch_bounds__(128) void k_pool(const float* __restrict__ X,
                                              const int* __restrict__ batch,
                                              const float* __restrict__ st,
                                              const float* __restrict__ g,
                                              const float* __restrict__ be,
                                              float* __restrict__ out) {
    int c = threadIdx.x;
    const float inv_n = 1.0f / (float)NN;
    float mu = st[c] * inv_n;
    float var = st[FF + c] * inv_n - mu * mu;
    float a = g[c] * rsqrtf(var + BN_EPS);
    float b = be[c] - mu * a;
    int chunk = (NN + gridDim.x - 1) / gridDim.x;
    int r0 = blockIdx.x * chunk;
    int r1 = min(r0 + chunk, NN);
    if (r0 >= r1) return;
    float acc = 0.f;
    int cnt = 0;
    int cur = batch[r0];
    for (int r = r0; r < r1; r++) {
        int bb = batch[r];
        if (bb != cur) {
            atomicAdd(&out[(size_t)cur * FF + c], fmaf(a, acc, b * (float)cnt));
            acc = 0.f;
            cnt = 0;
            cur = bb;
        }
        acc += X[(size_t)r * FF + c];
        cnt++;
    }
    atomicAdd(&out[(size_t)cur * FF + c], fmaf(a, acc, b * (float)cnt));
}

extern "C" void kernel_launch(void* const* d_in, const int* in_sizes, int n_in,
                              void* d_out, int out_size, void* d_ws, size_t ws_size,
                              hipStream_t stream) {
    const float* x = (const float*)d_in[0];
    const int* ei = (const int*)d_in[1];
    const int* src = ei;
    const int* dst = ei + NE;
    const int* batch = (const int*)d_in[2];
    const float* gc_W1 = (const float*)d_in[4];
    const float* gc_b1 = (const float*)d_in[5];
    const float* gc_W2 = (const float*)d_in[6];
    const float* gc_b2 = (const float*)d_in[7];
    const float* gc_g = (const float*)d_in[8];
    const float* gc_be = (const float*)d_in[9];
    const float* h0_W1 = (const float*)d_in[10];
    const float* h0_b1 = (const float*)d_in[11];
    const float* h0_W2 = (const float*)d_in[12];
    const float* h0_b2 = (const float*)d_in[13];
    const float* h0_g = (const float*)d_in[14];
    const float* h0_be = (const float*)d_in[15];
    const float* h1_W1 = (const float*)d_in[16];
    const float* h1_b1 = (const float*)d_in[17];
    const float* h1_W2 = (const float*)d_in[18];
    const float* h1_b2 = (const float*)d_in[19];
    const float* h1_g = (const float*)d_in[20];
    const float* h1_be = (const float*)d_in[21];

    const size_t NF = (size_t)NN * FF;
    float* P0 = (float*)d_ws;
    float* P1 = P0 + NF;
    float* P2 = P1 + NF;
    float* Wcat = P2 + NF;
    float* stats = Wcat + FF * FF;  // 5 sets of 256 floats
    int* deg = (int*)(stats + 5 * 256);
    int* cnt = deg + NN;
    int* offs = cnt + NN;
    int* csr = offs + (NN + 4);

    hipMemsetAsync(deg, 0, (size_t)2 * NN * sizeof(int), stream);
    hipMemsetAsync(stats, 0, 5 * 256 * sizeof(float), stream);
    hipMemsetAsync(d_out, 0, (size_t)GG * KF * DD * sizeof(float), stream);

    k_deg<<<(NE + 255) / 256, 256, 0, stream>>>(dst, deg);
    k_scan<<<1, 1024, 0, stream>>>(deg, offs);
    k_fill<<<(NE + 255) / 256, 256, 0, stream>>>(src, dst, offs, cnt, csr);

    const int agg_grid = NN / 8;             // 6250
    const int gemm_grid = (NN + 127) / 128;  // 391

    // ---- GC layers (BN+relu fused into next agg; stats fused into gemm2) ----
    // GC0
    k_agg<false, false><<<agg_grid, 256, 0, stream>>>(
        (const float4*)x, offs, csr, nullptr, nullptr, nullptr, (float4*)P0);
    gemm128<true, false><<<gemm_grid, 256, 0, stream>>>(P0, gc_W1, gc_b1, P1, NN, nullptr);
    gemm128<false, true><<<gemm_grid, 256, 0, stream>>>(P1, gc_W2, gc_b2, P2, NN, stats);
    // GC1
    k_agg<true, true><<<agg_grid, 256, 0, stream>>>(
        (const float4*)P2, offs, csr, stats, gc_g, gc_be, (float4*)P0);
    gemm128<true, false><<<gemm_grid, 256, 0, stream>>>(P0, gc_W1 + FF * FF, gc_b1 + FF, P1, NN, nullptr);
    gemm128<false, true><<<gemm_grid, 256, 0, stream>>>(P1, gc_W2 + FF * FF, gc_b2 + FF, P2, NN, stats + 256);
    // GC2
    k_agg<true, true><<<agg_grid, 256, 0, stream>>>(
        (const float4*)P2, offs, csr, stats + 256, gc_g + FF, gc_be + FF, (float4*)P0);
    gemm128<true, false><<<gemm_grid, 256, 0, stream>>>(P0, gc_W1 + 2 * FF * FF, gc_b1 + 2 * FF, P1, NN, nullptr);
    gemm128<false, true><<<gemm_grid, 256, 0, stream>>>(P1, gc_W2 + 2 * FF * FF, gc_b2 + 2 * FF, P2, NN, stats + 512);

    // ---- head layer 0 (GC2 BN fused into agg, no relu) ----
    k_repack<<<(FF * FF + 255) / 256, 256, 0, stream>>>(h0_W1, Wcat);
    k_agg<true, false><<<agg_grid, 256, 0, stream>>>(
        (const float4*)P2, offs, csr, stats + 512, gc_g + 2 * FF, gc_be + 2 * FF, (float4*)P0);
    gemm128<true, false><<<gemm_grid, 256, 0, stream>>>(P0, Wcat, h0_b1, P1, NN, nullptr);
    k_bdgemm<false><<<agg_grid, 256, 0, stream>>>((const float4*)P1, h0_W2, (const float4*)h0_b2, (float4*)P2);
    k_stats<<<128, 256, 0, stream>>>(P2, stats + 768, NN);

    // ---- head layer 1 (h0 BN+relu fused into agg) ----
    k_agg<true, true><<<agg_grid, 256, 0, stream>>>(
        (const float4*)P2, offs, csr, stats + 768, h0_g, h0_be, (float4*)P0);
    k_bdgemm<true><<<agg_grid, 256, 0, stream>>>((const float4*)P0, h1_W1, (const float4*)h1_b1, (float4*)P1);
    k_bdgemm<false><<<agg_grid, 256, 0, stream>>>((const float4*)P1, h1_W2, (const float4*)h1_b2, (float4*)P2);
    k_stats<<<128, 256, 0, stream>>>(P2, stats + 1024, NN);

    // ---- pool with fused final BN ----
    k_pool<<<512, 128, 0, stream>>>(P2, batch, stats + 1024, h1_g, h1_be, (float*)d_out);
}

// Round 3
// 849.590 us; speedup vs baseline: 2.0489x; 1.1494x over previous
//
#include <hip/hip_runtime.h>

#define NN 50000
#define NE 800000
#define FF 128
#define KF 8
#define DD 16
#define GG 512
#define BN_EPS 1e-5f
#define NB 196  // ceil(NN/256)

// ---------------- CSR build ----------------
__global__ void k_deg(const int* __restrict__ dst, int* __restrict__ deg) {
    int e = blockIdx.x * 256 + threadIdx.x;
    if (e < NE) atomicAdd(&deg[dst[e]], 1);
}

// per-block sums of deg
__global__ __launch_bounds__(256) void k_bsum(const int* __restrict__ deg, int* __restrict__ bsum) {
    int idx = blockIdx.x * 256 + threadIdx.x;
    int v = (idx < NN) ? deg[idx] : 0;
#pragma unroll
    for (int off = 32; off; off >>= 1) v += __shfl_down(v, off, 64);
    __shared__ int ws[4];
    if ((threadIdx.x & 63) == 0) ws[threadIdx.x >> 6] = v;
    __syncthreads();
    if (threadIdx.x == 0) bsum[blockIdx.x] = ws[0] + ws[1] + ws[2] + ws[3];
}

// single-block exclusive scan of NB block sums
__global__ __launch_bounds__(256) void k_bscan(const int* __restrict__ bsum, int* __restrict__ boffs) {
    __shared__ int s[256];
    int tid = threadIdx.x;
    int v = (tid < NB) ? bsum[tid] : 0;
    s[tid] = v;
    __syncthreads();
    for (int off = 1; off < 256; off <<= 1) {
        int t = (tid >= off) ? s[tid - off] : 0;
        __syncthreads();
        s[tid] += t;
        __syncthreads();
    }
    if (tid < NB) boffs[tid] = s[tid] - v;  // exclusive
}

// per-element offsets: block-local scan + block offset
__global__ __launch_bounds__(256) void k_offs(const int* __restrict__ deg,
                                              const int* __restrict__ boffs,
                                              int* __restrict__ offs) {
    __shared__ int s[256];
    int tid = threadIdx.x;
    int idx = blockIdx.x * 256 + tid;
    int v = (idx < NN) ? deg[idx] : 0;
    s[tid] = v;
    __syncthreads();
    for (int off = 1; off < 256; off <<= 1) {
        int t = (tid >= off) ? s[tid - off] : 0;
        __syncthreads();
        s[tid] += t;
        __syncthreads();
    }
    int incl = s[tid];
    if (idx < NN) offs[idx] = boffs[blockIdx.x] + incl - v;
    if (idx == NN - 1) offs[NN] = boffs[blockIdx.x] + incl;
}

__global__ void k_fill(const int* __restrict__ src, const int* __restrict__ dst,
                       const int* __restrict__ offs, int* __restrict__ cnt,
                       int* __restrict__ csr) {
    int e = blockIdx.x * 256 + threadIdx.x;
    if (e < NE) {
        int d = dst[e];
        int p = atomicAdd(&cnt[d], 1);
        csr[offs[d] + p] = src[e];
    }
}

// ---------------- aggregation with fused (optional) BN affine (+relu) on load ------
template <bool BN, bool RELU>
__global__ __launch_bounds__(256) void k_agg(const float4* __restrict__ X,
                                             const int* __restrict__ offs,
                                             const int* __restrict__ csr,
                                             const float* __restrict__ st,
                                             const float* __restrict__ g,
                                             const float* __restrict__ be,
                                             float4* __restrict__ Z) {
    int grp = threadIdx.x >> 5;
    int lane = threadIdx.x & 31;
    int n = blockIdx.x * 8 + grp;

    float4 a4 = make_float4(1.f, 1.f, 1.f, 1.f);
    float4 b4 = make_float4(0.f, 0.f, 0.f, 0.f);
    if (BN) {
        const float inv_n = 1.0f / (float)NN;
        float av[4], bv[4];
#pragma unroll
        for (int t = 0; t < 4; t++) {
            int c = lane * 4 + t;
            float mu = st[c] * inv_n;
            float var = st[FF + c] * inv_n - mu * mu;
            float a = g[c] * rsqrtf(var + BN_EPS);
            av[t] = a;
            bv[t] = be[c] - mu * a;
        }
        a4 = make_float4(av[0], av[1], av[2], av[3]);
        b4 = make_float4(bv[0], bv[1], bv[2], bv[3]);
    }

    auto apply = [&](float4 v) -> float4 {
        if (BN) {
            v.x = fmaf(v.x, a4.x, b4.x);
            v.y = fmaf(v.y, a4.y, b4.y);
            v.z = fmaf(v.z, a4.z, b4.z);
            v.w = fmaf(v.w, a4.w, b4.w);
        }
        if (RELU) {
            v.x = fmaxf(v.x, 0.f);
            v.y = fmaxf(v.y, 0.f);
            v.z = fmaxf(v.z, 0.f);
            v.w = fmaxf(v.w, 0.f);
        }
        return v;
    };
    auto add4 = [](float4& a, float4 b) {
        a.x += b.x; a.y += b.y; a.z += b.z; a.w += b.w;
    };

    float4 acc = apply(X[(size_t)n * 32 + lane]);
    int e0 = offs[n], e1 = offs[n + 1];
    int e = e0;
    for (; e + 8 <= e1; e += 8) {
        int s0 = csr[e], s1 = csr[e + 1], s2 = csr[e + 2], s3 = csr[e + 3];
        int s4 = csr[e + 4], s5 = csr[e + 5], s6 = csr[e + 6], s7 = csr[e + 7];
        float4 v0 = X[(size_t)s0 * 32 + lane];
        float4 v1 = X[(size_t)s1 * 32 + lane];
        float4 v2 = X[(size_t)s2 * 32 + lane];
        float4 v3 = X[(size_t)s3 * 32 + lane];
        float4 v4 = X[(size_t)s4 * 32 + lane];
        float4 v5 = X[(size_t)s5 * 32 + lane];
        float4 v6 = X[(size_t)s6 * 32 + lane];
        float4 v7 = X[(size_t)s7 * 32 + lane];
        v0 = apply(v0); v1 = apply(v1); v2 = apply(v2); v3 = apply(v3);
        v4 = apply(v4); v5 = apply(v5); v6 = apply(v6); v7 = apply(v7);
        add4(v0, v1); add4(v2, v3); add4(v4, v5); add4(v6, v7);
        add4(v0, v2); add4(v4, v6); add4(v0, v4); add4(acc, v0);
    }
    for (; e + 4 <= e1; e += 4) {
        int s0 = csr[e], s1 = csr[e + 1], s2 = csr[e + 2], s3 = csr[e + 3];
        float4 v0 = apply(X[(size_t)s0 * 32 + lane]);
        float4 v1 = apply(X[(size_t)s1 * 32 + lane]);
        float4 v2 = apply(X[(size_t)s2 * 32 + lane]);
        float4 v3 = apply(X[(size_t)s3 * 32 + lane]);
        add4(v0, v1); add4(v2, v3); add4(v0, v2); add4(acc, v0);
    }
    for (; e < e1; e++) {
        float4 v = apply(X[(size_t)csr[e] * 32 + lane]);
        add4(acc, v);
    }
    Z[(size_t)n * 32 + lane] = acc;
}

// ---------------- full GEMM: C[N,128] = act(A[N,128] @ W[128,128] + b), optional stats
template <bool RELU, bool STATS>
__global__ __launch_bounds__(256) void gemm128(const float* __restrict__ A,
                                               const float* __restrict__ W,
                                               const float* __restrict__ bias,
                                               float* __restrict__ C, int nrows,
                                               float* __restrict__ st) {
    __shared__ float As[128][33];
    __shared__ float Ws[32][128];
    int row0 = blockIdx.x * 128;
    int tid = threadIdx.x;
    int tr = (tid >> 4) << 3;
    int tc = (tid & 15) << 3;
    float acc[8][8];
#pragma unroll
    for (int i = 0; i < 8; i++)
#pragma unroll
        for (int j = 0; j < 8; j++) acc[i][j] = 0.f;

    for (int f0 = 0; f0 < 128; f0 += 32) {
#pragma unroll
        for (int i = 0; i < 4; i++) {
            int l = tid + i * 256;
            int r = l >> 3, q = l & 7;
            int gr = row0 + r;
            if (gr >= nrows) gr = nrows - 1;
            float4 v = ((const float4*)A)[(size_t)gr * 32 + (f0 >> 2) + q];
            As[r][q * 4 + 0] = v.x;
            As[r][q * 4 + 1] = v.y;
            As[r][q * 4 + 2] = v.z;
            As[r][q * 4 + 3] = v.w;
        }
#pragma unroll
        for (int i = 0; i < 4; i++) {
            int l = tid + i * 256;
            int f = l >> 5, q = l & 31;
            ((float4*)&Ws[f][0])[q] = ((const float4*)W)[(size_t)(f0 + f) * 32 + q];
        }
        __syncthreads();
#pragma unroll 8
        for (int f = 0; f < 32; f++) {
            float a[8];
#pragma unroll
            for (int i = 0; i < 8; i++) a[i] = As[tr + i][f];
            float4 w04 = *(const float4*)&Ws[f][tc];
            float4 w48 = *(const float4*)&Ws[f][tc + 4];
            float w[8] = {w04.x, w04.y, w04.z, w04.w, w48.x, w48.y, w48.z, w48.w};
#pragma unroll
            for (int i = 0; i < 8; i++)
#pragma unroll
                for (int j = 0; j < 8; j++) acc[i][j] = fmaf(a[i], w[j], acc[i][j]);
        }
        __syncthreads();
    }

    float cs[8], cq[8];
#pragma unroll
    for (int j = 0; j < 8; j++) { cs[j] = 0.f; cq[j] = 0.f; }
#pragma unroll
    for (int i = 0; i < 8; i++) {
        int r = row0 + tr + i;
        if (r < nrows) {
#pragma unroll
            for (int j = 0; j < 8; j++) {
                float v = acc[i][j] + bias[tc + j];
                if (RELU) v = fmaxf(v, 0.f);
                C[(size_t)r * 128 + tc + j] = v;
                if (STATS) { cs[j] += v; cq[j] += v * v; }
            }
        }
    }
    if (STATS) {
        float* S1 = &As[0][0];
        float* S2 = &Ws[0][0];
        int grp = tid >> 4;
        __syncthreads();
#pragma unroll
        for (int j = 0; j < 8; j++) {
            S1[grp * 128 + tc + j] = cs[j];
            S2[grp * 128 + tc + j] = cq[j];
        }
        __syncthreads();
        if (tid < 128) {
            float s = 0.f, q = 0.f;
#pragma unroll
            for (int gi = 0; gi < 16; gi++) {
                s += S1[gi * 128 + tid];
                q += S2[gi * 128 + tid];
            }
            atomicAdd(&st[tid], s);
            atomicAdd(&st[FF + tid], q);
        }
    }
}

#define KSTR 264  // padded k-block stride (floats): 16B-aligned, banks shift 8/k (2-way = free)

// ---------------- block-diagonal GEMM (K blocks of 16x16), 8 nodes/block ----------
template <bool RELU>
__global__ __launch_bounds__(256) void k_bdgemm(const float4* __restrict__ A,
                                                const float* __restrict__ W,
                                                const float4* __restrict__ bias,
                                                float4* __restrict__ C) {
    __shared__ float As[8][128];
    __shared__ float Ws[KF * KSTR];
    int grp = threadIdx.x >> 5, lane = threadIdx.x & 31;
    int n = blockIdx.x * 8 + grp;
    ((float4*)&As[grp][0])[lane] = A[(size_t)n * 32 + lane];
    for (int l = threadIdx.x; l < KF * 256; l += 256) {
        int k = l >> 8, r = l & 255;
        Ws[k * KSTR + r] = W[l];
    }
    __syncthreads();
    int k = lane >> 2, jb = (lane & 3) * 4;
    float a[16];
    {
        const float4* As4 = (const float4*)&As[grp][k * 16];
        float4 a0 = As4[0], a1 = As4[1], a2 = As4[2], a3 = As4[3];
        a[0] = a0.x; a[1] = a0.y; a[2] = a0.z; a[3] = a0.w;
        a[4] = a1.x; a[5] = a1.y; a[6] = a1.z; a[7] = a1.w;
        a[8] = a2.x; a[9] = a2.y; a[10] = a2.z; a[11] = a2.w;
        a[12] = a3.x; a[13] = a3.y; a[14] = a3.z; a[15] = a3.w;
    }
    const float* wp = &Ws[k * KSTR + jb];
    float4 acc = bias[lane];
#pragma unroll
    for (int i = 0; i < 16; i++) {
        float4 wv = *(const float4*)&wp[i * 16];
        acc.x = fmaf(a[i], wv.x, acc.x);
        acc.y = fmaf(a[i], wv.y, acc.y);
        acc.z = fmaf(a[i], wv.z, acc.z);
        acc.w = fmaf(a[i], wv.w, acc.w);
    }
    if (RELU) {
        acc.x = fmaxf(acc.x, 0.f);
        acc.y = fmaxf(acc.y, 0.f);
        acc.z = fmaxf(acc.z, 0.f);
        acc.w = fmaxf(acc.w, 0.f);
    }
    C[(size_t)n * 32 + lane] = acc;
}

// ---------------- fused double block-diagonal GEMM: out = (relu(z@W1+b1))@W2+b2 ----
__global__ __launch_bounds__(256) void k_bdgemm2(const float4* __restrict__ A,
                                                 const float* __restrict__ W1,
                                                 const float4* __restrict__ b1,
                                                 const float* __restrict__ W2,
                                                 const float4* __restrict__ b2,
                                                 float4* __restrict__ C) {
    __shared__ float As[8][128];
    __shared__ float Ts[8][128];
    __shared__ float Ws1[KF * KSTR];
    __shared__ float Ws2[KF * KSTR];
    int grp = threadIdx.x >> 5, lane = threadIdx.x & 31;
    int n = blockIdx.x * 8 + grp;
    ((float4*)&As[grp][0])[lane] = A[(size_t)n * 32 + lane];
    for (int l = threadIdx.x; l < KF * 256; l += 256) {
        int k = l >> 8, r = l & 255;
        Ws1[k * KSTR + r] = W1[l];
        Ws2[k * KSTR + r] = W2[l];
    }
    __syncthreads();
    int k = lane >> 2, jb = (lane & 3) * 4;
    float a[16];
    {
        const float4* As4 = (const float4*)&As[grp][k * 16];
        float4 a0 = As4[0], a1 = As4[1], a2 = As4[2], a3 = As4[3];
        a[0] = a0.x; a[1] = a0.y; a[2] = a0.z; a[3] = a0.w;
        a[4] = a1.x; a[5] = a1.y; a[6] = a1.z; a[7] = a1.w;
        a[8] = a2.x; a[9] = a2.y; a[10] = a2.z; a[11] = a2.w;
        a[12] = a3.x; a[13] = a3.y; a[14] = a3.z; a[15] = a3.w;
    }
    const float* wp1 = &Ws1[k * KSTR + jb];
    float4 t = b1[lane];
#pragma unroll
    for (int i = 0; i < 16; i++) {
        float4 wv = *(const float4*)&wp1[i * 16];
        t.x = fmaf(a[i], wv.x, t.x);
        t.y = fmaf(a[i], wv.y, t.y);
        t.z = fmaf(a[i], wv.z, t.z);
        t.w = fmaf(a[i], wv.w, t.w);
    }
    t.x = fmaxf(t.x, 0.f); t.y = fmaxf(t.y, 0.f);
    t.z = fmaxf(t.z, 0.f); t.w = fmaxf(t.w, 0.f);
    ((float4*)&Ts[grp][0])[lane] = t;
    __syncthreads();
    float b[16];
    {
        const float4* Ts4 = (const float4*)&Ts[grp][k * 16];
        float4 a0 = Ts4[0], a1 = Ts4[1], a2 = Ts4[2], a3 = Ts4[3];
        b[0] = a0.x; b[1] = a0.y; b[2] = a0.z; b[3] = a0.w;
        b[4] = a1.x; b[5] = a1.y; b[6] = a1.z; b[7] = a1.w;
        b[8] = a2.x; b[9] = a2.y; b[10] = a2.z; b[11] = a2.w;
        b[12] = a3.x; b[13] = a3.y; b[14] = a3.z; b[15] = a3.w;
    }
    const float* wp2 = &Ws2[k * KSTR + jb];
    float4 acc = b2[lane];
#pragma unroll
    for (int i = 0; i < 16; i++) {
        float4 wv = *(const float4*)&wp2[i * 16];
        acc.x = fmaf(b[i], wv.x, acc.x);
        acc.y = fmaf(b[i], wv.y, acc.y);
        acc.z = fmaf(b[i], wv.z, acc.z);
        acc.w = fmaf(b[i], wv.w, acc.w);
    }
    C[(size_t)n * 32 + lane] = acc;
}

// ---------------- BN stats (standalone, for bdgemm outputs) ----------------
__global__ __launch_bounds__(256) void k_stats(const float* __restrict__ X,
                                               float* __restrict__ st, int nrows) {
    int c = threadIdx.x & 127;
    int half = threadIdx.x >> 7;
    int rpb = (nrows + gridDim.x - 1) / gridDim.x;
    int r0 = blockIdx.x * rpb;
    int r1 = min(r0 + rpb, nrows);
    float s = 0.f, sq = 0.f;
    for (int r = r0 + half; r < r1; r += 2) {
        float v = X[(size_t)r * FF + c];
        s += v;
        sq += v * v;
    }
    atomicAdd(&st[c], s);
    atomicAdd(&st[FF + c], sq);
}

// ---------------- repack h0_W1 [K,F,d] -> Wcat [F, K*d] ----------------
__global__ void k_repack(const float* __restrict__ W1, float* __restrict__ Wcat) {
    int idx = blockIdx.x * 256 + threadIdx.x;
    if (idx < FF * FF) {
        int f = idx >> 7, c = idx & 127;
        int k = c >> 4, j = c & 15;
        Wcat[idx] = W1[k * (FF * DD) + f * DD + j];
    }
}

// ---------------- pooling with fused final BN ----------------
__global__ __launch_bounds__(128) void k_pool(const float* __restrict__ X,
                                              const int* __restrict__ batch,
                                              const float* __restrict__ st,
                                              const float* __restrict__ g,
                                              const float* __restrict__ be,
                                              float* __restrict__ out) {
    int c = threadIdx.x;
    const float inv_n = 1.0f / (float)NN;
    float mu = st[c] * inv_n;
    float var = st[FF + c] * inv_n - mu * mu;
    float a = g[c] * rsqrtf(var + BN_EPS);
    float b = be[c] - mu * a;
    int chunk = (NN + gridDim.x - 1) / gridDim.x;
    int r0 = blockIdx.x * chunk;
    int r1 = min(r0 + chunk, NN);
    if (r0 >= r1) return;
    float acc = 0.f;
    int cnt = 0;
    int cur = batch[r0];
    for (int r = r0; r < r1; r++) {
        int bb = batch[r];
        if (bb != cur) {
            atomicAdd(&out[(size_t)cur * FF + c], fmaf(a, acc, b * (float)cnt));
            acc = 0.f;
            cnt = 0;
            cur = bb;
        }
        acc += X[(size_t)r * FF + c];
        cnt++;
    }
    atomicAdd(&out[(size_t)cur * FF + c], fmaf(a, acc, b * (float)cnt));
}

extern "C" void kernel_launch(void* const* d_in, const int* in_sizes, int n_in,
                              void* d_out, int out_size, void* d_ws, size_t ws_size,
                              hipStream_t stream) {
    const float* x = (const float*)d_in[0];
    const int* ei = (const int*)d_in[1];
    const int* src = ei;
    const int* dst = ei + NE;
    const int* batch = (const int*)d_in[2];
    const float* gc_W1 = (const float*)d_in[4];
    const float* gc_b1 = (const float*)d_in[5];
    const float* gc_W2 = (const float*)d_in[6];
    const float* gc_b2 = (const float*)d_in[7];
    const float* gc_g = (const float*)d_in[8];
    const float* gc_be = (const float*)d_in[9];
    const float* h0_W1 = (const float*)d_in[10];
    const float* h0_b1 = (const float*)d_in[11];
    const float* h0_W2 = (const float*)d_in[12];
    const float* h0_b2 = (const float*)d_in[13];
    const float* h0_g = (const float*)d_in[14];
    const float* h0_be = (const float*)d_in[15];
    const float* h1_W1 = (const float*)d_in[16];
    const float* h1_b1 = (const float*)d_in[17];
    const float* h1_W2 = (const float*)d_in[18];
    const float* h1_b2 = (const float*)d_in[19];
    const float* h1_g = (const float*)d_in[20];
    const float* h1_be = (const float*)d_in[21];

    const size_t NF = (size_t)NN * FF;
    float* P0 = (float*)d_ws;
    float* P1 = P0 + NF;
    float* P2 = P1 + NF;
    float* Wcat = P2 + NF;
    float* stats = Wcat + FF * FF;
    int* deg = (int*)(stats + 5 * 256);
    int* cnt = deg + NN;
    int* offs = cnt + NN;
    int* bsum = offs + (NN + 4);
    int* boffs = bsum + 256;
    int* csr = boffs + 256;

    hipMemsetAsync(deg, 0, (size_t)2 * NN * sizeof(int), stream);
    hipMemsetAsync(stats, 0, 5 * 256 * sizeof(float), stream);
    hipMemsetAsync(d_out, 0, (size_t)GG * KF * DD * sizeof(float), stream);

    k_deg<<<(NE + 255) / 256, 256, 0, stream>>>(dst, deg);
    k_bsum<<<NB, 256, 0, stream>>>(deg, bsum);
    k_bscan<<<1, 256, 0, stream>>>(bsum, boffs);
    k_offs<<<NB, 256, 0, stream>>>(deg, boffs, offs);
    k_fill<<<(NE + 255) / 256, 256, 0, stream>>>(src, dst, offs, cnt, csr);

    const int agg_grid = NN / 8;             // 6250
    const int gemm_grid = (NN + 127) / 128;  // 391

    // ---- GC layers ----
    k_agg<false, false><<<agg_grid, 256, 0, stream>>>(
        (const float4*)x, offs, csr, nullptr, nullptr, nullptr, (float4*)P0);
    gemm128<true, false><<<gemm_grid, 256, 0, stream>>>(P0, gc_W1, gc_b1, P1, NN, nullptr);
    gemm128<false, true><<<gemm_grid, 256, 0, stream>>>(P1, gc_W2, gc_b2, P2, NN, stats);

    k_agg<true, true><<<agg_grid, 256, 0, stream>>>(
        (const float4*)P2, offs, csr, stats, gc_g, gc_be, (float4*)P0);
    gemm128<true, false><<<gemm_grid, 256, 0, stream>>>(P0, gc_W1 + FF * FF, gc_b1 + FF, P1, NN, nullptr);
    gemm128<false, true><<<gemm_grid, 256, 0, stream>>>(P1, gc_W2 + FF * FF, gc_b2 + FF, P2, NN, stats + 256);

    k_agg<true, true><<<agg_grid, 256, 0, stream>>>(
        (const float4*)P2, offs, csr, stats + 256, gc_g + FF, gc_be + FF, (float4*)P0);
    gemm128<true, false><<<gemm_grid, 256, 0, stream>>>(P0, gc_W1 + 2 * FF * FF, gc_b1 + 2 * FF, P1, NN, nullptr);
    gemm128<false, true><<<gemm_grid, 256, 0, stream>>>(P1, gc_W2 + 2 * FF * FF, gc_b2 + 2 * FF, P2, NN, stats + 512);

    // ---- head layer 0 ----
    k_repack<<<(FF * FF + 255) / 256, 256, 0, stream>>>(h0_W1, Wcat);
    k_agg<true, false><<<agg_grid, 256, 0, stream>>>(
        (const float4*)P2, offs, csr, stats + 512, gc_g + 2 * FF, gc_be + 2 * FF, (float4*)P0);
    gemm128<true, false><<<gemm_grid, 256, 0, stream>>>(P0, Wcat, h0_b1, P1, NN, nullptr);
    k_bdgemm<false><<<agg_grid, 256, 0, stream>>>((const float4*)P1, h0_W2, (const float4*)h0_b2, (float4*)P2);
    k_stats<<<256, 256, 0, stream>>>(P2, stats + 768, NN);

    // ---- head layer 1 (fused bdgemm pair) ----
    k_agg<true, true><<<agg_grid, 256, 0, stream>>>(
        (const float4*)P2, offs, csr, stats + 768, h0_g, h0_be, (float4*)P0);
    k_bdgemm2<<<agg_grid, 256, 0, stream>>>((const float4*)P0, h1_W1, (const float4*)h1_b1,
                                            h1_W2, (const float4*)h1_b2, (float4*)P1);
    k_stats<<<256, 256, 0, stream>>>(P1, stats + 1024, NN);

    // ---- pool with fused final BN ----
    k_pool<<<512, 128, 0, stream>>>(P1, batch, stats + 1024, h1_g, h1_be, (float*)d_out);
}